// Round 1
// 437.515 us; speedup vs baseline: 1.2632x; 1.2632x over previous
//
#include <hip/hip_runtime.h>

// Problem dims
#define B_  32
#define N_  1024
#define E_  1024
#define H_  8
#define D_  128
#define MID_ 64
#define NT_  16        // n-tiles for fused score+pool (64 rows each)
#define TR_  64        // rows per tile = N_/NT_
#define NS2_ 16        // n-splits for v2 pooling (64 rows each)

// All inputs are float32 (verified: threshold = 2%*max|ref| with no bf16 floor
// => _any_bf16 false). Output is float32 (reference returns jnp.float32).

// ---------------------------------------------------------------------------
// K1: per (b,h): Q[d] = query[b]·Wq_row(h*D+d) + bq ; qb[b,h] = Q·bk_slice
//     qk[b,h,e] = sum_d Q[d] * Wk[h*D+d, e]
// grid 256 blocks (b*8+h), 256 threads
// ---------------------------------------------------------------------------
__global__ __launch_bounds__(256) void k_qkproj(
        const float* __restrict__ query, const float* __restrict__ Wq,
        const float* __restrict__ bq, const float* __restrict__ Wk,
        const float* __restrict__ bk, float* __restrict__ qk,
        float* __restrict__ qb)
{
    const int bh = blockIdx.x;
    const int b = bh >> 3, h = bh & 7;
    const int t = threadIdx.x;

    __shared__ float Qp[2][D_];
    __shared__ float Qs[D_];
    __shared__ float red[2];

    // phase A: Q slice, 2 threads per d (e split in halves of 512)
    {
        const int d = t & 127, half = t >> 7;
        const int row = h * D_ + d;
        const float4* wr = (const float4*)(Wq + (size_t)row * E_) + half * 128;
        const float4* qr = (const float4*)(query + (size_t)b * E_) + half * 128;
        float acc = 0.f;
        for (int i = 0; i < 128; ++i) {
            float4 w = wr[i], q = qr[i];
            acc += w.x * q.x + w.y * q.y + w.z * q.z + w.w * q.w;
        }
        Qp[half][d] = acc;
    }
    __syncthreads();
    if (t < D_) {
        const int row = h * D_ + t;
        float q = Qp[0][t] + Qp[1][t] + bq[row];
        Qs[t] = q;
        float qp = q * bk[row];
        #pragma unroll
        for (int off = 32; off; off >>= 1) qp += __shfl_down(qp, off);
        if ((t & 63) == 0) red[t >> 6] = qp;
    }
    __syncthreads();
    if (t == 0) qb[bh] = red[0] + red[1];

    // phase B: qk row, thread owns 4 e's (coalesced float4 per d-iteration)
    const int e0 = t * 4;
    float4 a = make_float4(0.f, 0.f, 0.f, 0.f);
    const float* wkb = Wk + (size_t)(h * D_) * E_ + e0;
    for (int d = 0; d < D_; ++d) {
        float Qd = Qs[d];
        float4 w = *(const float4*)(wkb + (size_t)d * E_);
        a.x += Qd * w.x; a.y += Qd * w.y; a.z += Qd * w.z; a.w += Qd * w.w;
    }
    *(float4*)(qk + (size_t)bh * E_ + e0) = a;
}

// ---------------------------------------------------------------------------
// K2 (fused): per (tile,b):
//   stage qk[b] (8x1024 f32 = 32KB) into LDS once.
//   phase1: s[n,h] = (key[n]·qk[h] + qb[h]) / sqrt(D) for 64 rows (to LDS).
//     layout: c = t&31 owns e-chunks {(i*32+c)*4}, g = t>>5 owns 4 rows.
//     => every key load instruction covers 2 full 512B segments (coalesced),
//        every LDS qf read (broadcast pair, conflict-free) feeds 4 row-FMAs.
//     butterfly shfl_xor allreduce over the 32-lane group; lanes c<8 store s.
//   phase2: atomicAdd PP[b,h,e] += sum_{n in tile} s[n,h]*key[n,e] (L2-hot)
// grid (NT_=16, B_), 256 threads -> 512 blocks (was 128: latency-bound)
// ---------------------------------------------------------------------------
__global__ __launch_bounds__(256) void k_scorepool(
        const float* __restrict__ key, const float* __restrict__ qk,
        const float* __restrict__ qb, float* __restrict__ PP,
        float* __restrict__ ssum)
{
    const int tile = blockIdx.x, b = blockIdx.y;
    const int t = threadIdx.x;
    const int c = t & 31, g = t >> 5;     // 8 groups of 32 lanes

    __shared__ __align__(16) float qks[H_ * E_];   // 32 KB
    __shared__ __align__(16) float ssc[TR_][H_];   // 2 KB

    // stage qk[b] into LDS, coalesced float4
    {
        const float4* src = (const float4*)(qk + (size_t)b * H_ * E_);
        float4* dst = (float4*)qks;
        #pragma unroll
        for (int k = 0; k < 8; ++k) dst[t + k * 256] = src[t + k * 256];
    }
    __syncthreads();

    const float scale = 0.08838834764831845f;  // 1/sqrt(128)
    const float* keyb = key + ((size_t)b * N_ + (size_t)tile * TR_) * E_;
    const float4* qks4 = (const float4*)qks;
    const float qbv = qb[b * 8 + (c & 7)];     // lane c==h uses qb[b,h]

    float tsum = 0.f;                          // valid on lanes c<8 (h=c)
    #pragma unroll
    for (int p = 0; p < 2; ++p) {
        // rows r = p*32 + g*4 + j, j=0..3
        float acc[H_][4];
        #pragma unroll
        for (int h = 0; h < H_; ++h)
            #pragma unroll
            for (int j = 0; j < 4; ++j) acc[h][j] = 0.f;

        const float4* kr[4];
        #pragma unroll
        for (int j = 0; j < 4; ++j)
            kr[j] = (const float4*)(keyb + (size_t)(p * 32 + g * 4 + j) * E_);

        #pragma unroll 4
        for (int i = 0; i < 8; ++i) {
            float4 kf[4];
            #pragma unroll
            for (int j = 0; j < 4; ++j) kf[j] = kr[j][i * 32 + c];
            #pragma unroll
            for (int h = 0; h < H_; ++h) {
                float4 qf = qks4[h * 256 + i * 32 + c];
                #pragma unroll
                for (int j = 0; j < 4; ++j) {
                    acc[h][j] += qf.x * kf[j].x + qf.y * kf[j].y
                               + qf.z * kf[j].z + qf.w * kf[j].w;
                }
            }
        }
        // butterfly allreduce over the 32 lanes of this group
        #pragma unroll
        for (int off = 16; off; off >>= 1) {
            #pragma unroll
            for (int h = 0; h < H_; ++h)
                #pragma unroll
                for (int j = 0; j < 4; ++j)
                    acc[h][j] += __shfl_xor(acc[h][j], off);
        }
        // lanes c<8 store s for h=c (compile-time indices only, no scratch)
        const int r0 = p * 32 + g * 4;
        #pragma unroll
        for (int h = 0; h < H_; ++h) {
            if (c == h) {
                #pragma unroll
                for (int j = 0; j < 4; ++j) {
                    float s = (acc[h][j] + qbv) * scale;
                    ssc[r0 + j][h] = s;
                    tsum += s;
                }
            }
        }
    }
    if (c < H_) atomicAdd(&ssum[b * 8 + c], tsum);
    __syncthreads();

    // phase 2: thread owns 4 e's; loop tile's 64 rows (L2/L3-hot re-read)
    {
        const int e0 = t * 4;
        float pacc[H_][4] = {};
        const float* kb = keyb + e0;
        #pragma unroll 4
        for (int n = 0; n < TR_; ++n) {
            float4 kv = *(const float4*)(kb + (size_t)n * E_);
            float4 s0 = *(const float4*)&ssc[n][0];
            float4 s1 = *(const float4*)&ssc[n][4];
            pacc[0][0] += s0.x * kv.x; pacc[0][1] += s0.x * kv.y;
            pacc[0][2] += s0.x * kv.z; pacc[0][3] += s0.x * kv.w;
            pacc[1][0] += s0.y * kv.x; pacc[1][1] += s0.y * kv.y;
            pacc[1][2] += s0.y * kv.z; pacc[1][3] += s0.y * kv.w;
            pacc[2][0] += s0.z * kv.x; pacc[2][1] += s0.z * kv.y;
            pacc[2][2] += s0.z * kv.z; pacc[2][3] += s0.z * kv.w;
            pacc[3][0] += s0.w * kv.x; pacc[3][1] += s0.w * kv.y;
            pacc[3][2] += s0.w * kv.z; pacc[3][3] += s0.w * kv.w;
            pacc[4][0] += s1.x * kv.x; pacc[4][1] += s1.x * kv.y;
            pacc[4][2] += s1.x * kv.z; pacc[4][3] += s1.x * kv.w;
            pacc[5][0] += s1.y * kv.x; pacc[5][1] += s1.y * kv.y;
            pacc[5][2] += s1.y * kv.z; pacc[5][3] += s1.y * kv.w;
            pacc[6][0] += s1.z * kv.x; pacc[6][1] += s1.z * kv.y;
            pacc[6][2] += s1.z * kv.z; pacc[6][3] += s1.z * kv.w;
            pacc[7][0] += s1.w * kv.x; pacc[7][1] += s1.w * kv.y;
            pacc[7][2] += s1.w * kv.z; pacc[7][3] += s1.w * kv.w;
        }
        #pragma unroll
        for (int h = 0; h < H_; ++h) {
            float* dst = PP + ((size_t)(b * H_) + h) * E_ + e0;
            atomicAdd(dst + 0, pacc[h][0]); atomicAdd(dst + 1, pacc[h][1]);
            atomicAdd(dst + 2, pacc[h][2]); atomicAdd(dst + 3, pacc[h][3]);
        }
    }
}

// ---------------------------------------------------------------------------
// K3: P2[b,e] += sum_{n in split, mask=1} value2[b,n,e]  (atomic over splits)
// mask compacted into an LDS row list -> unconditional, pipelineable loads
// grid (NS2_=16, B_), 256 threads
// ---------------------------------------------------------------------------
__global__ __launch_bounds__(256) void k_pool_v2(
        const float* __restrict__ value2, const int* __restrict__ mask,
        float* __restrict__ P2)
{
    const int ns = blockIdx.x, b = blockIdx.y;
    const int t = threadIdx.x, e0 = t * 4;
    const int n0 = ns * (N_ / NS2_);   // 64 rows per split

    __shared__ int rows[N_ / NS2_];
    __shared__ int nrows;
    if (t == 0) nrows = 0;
    __syncthreads();
    if (t < N_ / NS2_) {
        if (mask[b * N_ + n0 + t]) {
            int idx = atomicAdd(&nrows, 1);
            rows[idx] = t;
        }
    }
    __syncthreads();
    const int nr = nrows;

    float a0 = 0.f, a1 = 0.f, a2 = 0.f, a3 = 0.f;
    const float* vb = value2 + ((size_t)(b * N_ + n0)) * E_ + e0;
    for (int i = 0; i < nr; ++i) {
        float4 v = *(const float4*)(vb + (size_t)rows[i] * E_);
        a0 += v.x; a1 += v.y; a2 += v.z; a3 += v.w;
    }
    float* dst = P2 + (size_t)b * E_ + e0;
    atomicAdd(dst + 0, a0); atomicAdd(dst + 1, a1);
    atomicAdd(dst + 2, a2); atomicAdd(dst + 3, a3);
}

// ---------------------------------------------------------------------------
// K4: final. per (b,h), 256 threads (t = half*128 + d; e-split halves)
//  attended_d = PP[b,h]·Wv_row(h*D+d) + ssum*bv_d
//  hv_m = relu(attended·Wb_m + bb_m)        (h constant over n → mask-pool = h)
//  alphac_d = sigmoid(sum_m hv_m*Wl2[d,m] + bl2_d)
//  v2a_d = P2[b]·Wv_row/cnt + bv_d          (softmax of uniform = mask/cnt)
//  out = f32(v1 * v2a * alphac)
// ---------------------------------------------------------------------------
__global__ __launch_bounds__(256) void k_final(
        const float* __restrict__ PP, const float* __restrict__ P2,
        const float* __restrict__ ssumg, const int* __restrict__ mask,
        const float* __restrict__ Wv, const float* __restrict__ bv,
        const float* __restrict__ Wb, const float* __restrict__ bb,
        const float* __restrict__ Wl2, const float* __restrict__ bl2,
        const float* __restrict__ value1, float* __restrict__ out)
{
    const int bh = blockIdx.x, b = bh >> 3, h = bh & 7;
    const int t = threadIdx.x;
    const int d = t & 127, half = t >> 7;

    __shared__ __align__(16) float pooled[E_];
    __shared__ __align__(16) float pool2[E_];
    __shared__ float attA[2][D_];
    __shared__ float attV[2][D_];
    __shared__ float att[D_];
    __shared__ float hv[MID_];
    __shared__ float red2[4];
    __shared__ float cnt_s;

    {
        const float4* pp = (const float4*)(PP + ((size_t)(b * H_) + h) * E_);
        const float4* p2 = (const float4*)(P2 + (size_t)b * E_);
        ((float4*)pooled)[t] = pp[t];
        ((float4*)pool2)[t]  = p2[t];

        int ci = 0;
        #pragma unroll
        for (int i = 0; i < 4; ++i) ci += mask[b * N_ + t + i * 256];
        float cf = (float)ci;
        #pragma unroll
        for (int off = 32; off; off >>= 1) cf += __shfl_down(cf, off);
        if ((t & 63) == 0) red2[t >> 6] = cf;
    }
    __syncthreads();
    if (t == 0) cnt_s = red2[0] + red2[1] + red2[2] + red2[3];

    const float ss = ssumg[bh];
    const float4* wv = (const float4*)(Wv + ((size_t)(h * D_ + d)) * E_) + half * 128;
    float accA = 0.f, accV = 0.f;
    #pragma unroll 4
    for (int i = 0; i < 128; ++i) {
        float4 w = wv[i];
        float4 pa = ((const float4*)pooled)[half * 128 + i];
        float4 pb = ((const float4*)pool2)[half * 128 + i];
        accA += pa.x * w.x + pa.y * w.y + pa.z * w.z + pa.w * w.w;
        accV += pb.x * w.x + pb.y * w.y + pb.z * w.z + pb.w * w.w;
    }
    attA[half][d] = accA;
    attV[half][d] = accV;
    __syncthreads();
    const float cnt = cnt_s;
    if (t < D_) att[t] = attA[0][t] + attA[1][t] + ss * bv[h * D_ + t];
    __syncthreads();
    if (t < MID_) {
        float a = bb[t];
        #pragma unroll 4
        for (int d2 = 0; d2 < D_; ++d2) a += att[d2] * Wb[t * D_ + d2];
        hv[t] = fmaxf(a, 0.f);
    }
    __syncthreads();
    if (t < D_) {
        float z = bl2[t];
        #pragma unroll
        for (int m = 0; m < MID_; ++m) z += hv[m] * Wl2[t * MID_ + m];
        float alphac = 1.f / (1.f + expf(-z));
        const float bvd = bv[h * D_ + t];
        float v2a = (attV[0][t] + attV[1][t]) / cnt + bvd;
        out[(size_t)b * E_ + h * D_ + t] =
            value1[(size_t)b * E_ + h * D_ + t] * v2a * alphac;
    }
}

// ---------------------------------------------------------------------------
extern "C" void kernel_launch(void* const* d_in, const int* in_sizes, int n_in,
                              void* d_out, int out_size, void* d_ws, size_t ws_size,
                              hipStream_t stream)
{
    const float* query  = (const float*)d_in[0];
    const float* key    = (const float*)d_in[1];
    const int*   mask   = (const int*)d_in[2];
    const float* value1 = (const float*)d_in[3];
    const float* value2 = (const float*)d_in[4];
    const float* Wq  = (const float*)d_in[5];
    const float* bq  = (const float*)d_in[6];
    const float* Wk  = (const float*)d_in[7];
    const float* bk  = (const float*)d_in[8];
    const float* Wv  = (const float*)d_in[9];
    const float* bv  = (const float*)d_in[10];
    const float* Wb  = (const float*)d_in[11];
    const float* bb  = (const float*)d_in[12];
    // d_in[13] = Wl, d_in[14] = bl: eliminated (softmax over identical values = mask/cnt)
    const float* Wl2 = (const float*)d_in[15];
    const float* bl2 = (const float*)d_in[16];
    float* out = (float*)d_out;

    // workspace layout (bytes), total ~2.13 MB
    char* ws = (char*)d_ws;
    const size_t OFF_P2 = (size_t)B_ * H_ * E_ * 4;     // PP: 1 MB
    const size_t OFF_SS = OFF_P2 + (size_t)B_ * E_ * 4; // P2: 128 KB
    const size_t OFF_QB = OFF_SS + 1024;                // ssum: 1 KB
    const size_t OFF_QK = OFF_QB + 1024;                // qb: 1 KB
    float* PP   = (float*)(ws);
    float* P2   = (float*)(ws + OFF_P2);
    float* ssum = (float*)(ws + OFF_SS);
    float* qb   = (float*)(ws + OFF_QB);
    float* qk   = (float*)(ws + OFF_QK);                // 1 MB

    // zero the atomic-accumulated region (PP, P2, ssum); stream-ordered, capture-safe
    hipMemsetAsync(d_ws, 0, OFF_QB, stream);

    hipLaunchKernelGGL(k_qkproj, dim3(B_ * H_), dim3(256), 0, stream,
                       query, Wq, bq, Wk, bk, qk, qb);
    hipLaunchKernelGGL(k_scorepool, dim3(NT_, B_), dim3(256), 0, stream,
                       key, qk, qb, PP, ssum);
    hipLaunchKernelGGL(k_pool_v2, dim3(NS2_, B_), dim3(256), 0, stream,
                       value2, mask, P2);
    hipLaunchKernelGGL(k_final, dim3(B_ * H_), dim3(256), 0, stream,
                       PP, P2, ssum, mask, Wv, bv, Wb, bb, Wl2, bl2, value1, out);
}

// Round 2
// 426.981 us; speedup vs baseline: 1.2944x; 1.0247x over previous
//
#include <hip/hip_runtime.h>

// Problem dims
#define B_  32
#define N_  1024
#define E_  1024
#define H_  8
#define D_  128
#define MID_ 64
#define NT_  16        // n-tiles for fused score+pool (64 rows each)
#define TR_  64        // rows per tile = N_/NT_
#define NS2_ 16        // n-splits for v2 pooling (64 rows each)

// All inputs are float32 (verified: threshold = 2%*max|ref| with no bf16 floor
// => _any_bf16 false). Output is float32 (reference returns jnp.float32).

// ---------------------------------------------------------------------------
// kA (fused): blocks [0,256): qkproj per (b,h); blocks [256,768): v2 pooling.
// The two are data-independent; fusing overlaps qkproj's L3-bound weight
// streams with pooling's HBM-bound value2 stream (both were latency-bound
// at <=2 blocks/CU when run serially).
// ---------------------------------------------------------------------------
__global__ __launch_bounds__(256) void k_pre(
        const float* __restrict__ query, const float* __restrict__ Wq,
        const float* __restrict__ bq, const float* __restrict__ Wk,
        const float* __restrict__ bk, float* __restrict__ qk,
        float* __restrict__ qb,
        const float* __restrict__ value2, const int* __restrict__ mask,
        float* __restrict__ P2)
{
    const int t = threadIdx.x;

    __shared__ float Qp[2][D_];
    __shared__ float Qs[D_];
    __shared__ float red[2];
    __shared__ int rows[N_ / NS2_];
    __shared__ int nrows;

    if (blockIdx.x < 256) {
        // ---- qkproj: Q[d] = query[b]·Wq_row(h*D+d)+bq; qb = Q·bk; qk = Q@Wk_h
        const int bh = blockIdx.x;
        const int b = bh >> 3, h = bh & 7;

        // phase A: Q slice, 2 threads per d (e split in halves of 512)
        {
            const int d = t & 127, half = t >> 7;
            const int row = h * D_ + d;
            const float4* wr = (const float4*)(Wq + (size_t)row * E_) + half * 128;
            const float4* qr = (const float4*)(query + (size_t)b * E_) + half * 128;
            float acc = 0.f;
            #pragma unroll 8
            for (int i = 0; i < 128; ++i) {
                float4 w = wr[i], q = qr[i];
                acc += w.x * q.x + w.y * q.y + w.z * q.z + w.w * q.w;
            }
            Qp[half][d] = acc;
        }
        __syncthreads();
        if (t < D_) {
            const int row = h * D_ + t;
            float q = Qp[0][t] + Qp[1][t] + bq[row];
            Qs[t] = q;
            float qp = q * bk[row];
            #pragma unroll
            for (int off = 32; off; off >>= 1) qp += __shfl_down(qp, off);
            if ((t & 63) == 0) red[t >> 6] = qp;
        }
        __syncthreads();
        if (t == 0) qb[bh] = red[0] + red[1];

        // phase B: qk row, thread owns 4 e's (coalesced float4 per d-iter)
        const int e0 = t * 4;
        float4 a = make_float4(0.f, 0.f, 0.f, 0.f);
        const float* wkb = Wk + (size_t)(h * D_) * E_ + e0;
        #pragma unroll 8
        for (int d = 0; d < D_; ++d) {
            float Qd = Qs[d];
            float4 w = *(const float4*)(wkb + (size_t)d * E_);
            a.x += Qd * w.x; a.y += Qd * w.y; a.z += Qd * w.z; a.w += Qd * w.w;
        }
        *(float4*)(qk + (size_t)bh * E_ + e0) = a;
    } else {
        // ---- v2 pooling: P2[b,e] += sum_{n in split, mask=1} value2[b,n,e]
        const int idx = blockIdx.x - 256;
        const int b = idx & 31, ns = idx >> 5;
        const int e0 = t * 4;
        const int n0 = ns * (N_ / NS2_);   // 64 rows per split

        if (t == 0) nrows = 0;
        __syncthreads();
        if (t < N_ / NS2_) {
            if (mask[b * N_ + n0 + t]) {
                int i2 = atomicAdd(&nrows, 1);
                rows[i2] = t;
            }
        }
        __syncthreads();
        const int nr = nrows;

        float a0 = 0.f, a1 = 0.f, a2 = 0.f, a3 = 0.f;
        const float* vb = value2 + ((size_t)(b * N_ + n0)) * E_ + e0;
        #pragma unroll 4
        for (int i = 0; i < nr; ++i) {
            float4 v = *(const float4*)(vb + (size_t)rows[i] * E_);
            a0 += v.x; a1 += v.y; a2 += v.z; a3 += v.w;
        }
        float* dst = P2 + (size_t)b * E_ + e0;
        atomicAdd(dst + 0, a0); atomicAdd(dst + 1, a1);
        atomicAdd(dst + 2, a2); atomicAdd(dst + 3, a3);
    }
}

// ---------------------------------------------------------------------------
// K2 (fused): per (tile,b):
//   stage qk[b] (8x1024 f32 = 32KB) into LDS once.
//   phase1: s[n,h] = (key[n]·qk[h] + qb[h]) / sqrt(D) for 64 rows (to LDS).
//     layout: c = t&31 owns e-chunks, g = t>>5 owns 8 rows (single pass —
//     was 2 passes of 4: doubles independent loads per wait point, halves
//     shuffle-reduce overhead per byte).
//   phase2: atomicAdd PP[b,h,e] += sum_{n in tile} s[n,h]*key[n,e] (L3-hot)
// grid (NT_=16, B_), 256 threads
// ---------------------------------------------------------------------------
__global__ __launch_bounds__(256) void k_scorepool(
        const float* __restrict__ key, const float* __restrict__ qk,
        const float* __restrict__ qb, float* __restrict__ PP,
        float* __restrict__ ssum)
{
    const int tile = blockIdx.x, b = blockIdx.y;
    const int t = threadIdx.x;
    const int c = t & 31, g = t >> 5;     // 8 groups of 32 lanes

    __shared__ __align__(16) float qks[H_ * E_];   // 32 KB
    __shared__ __align__(16) float ssc[TR_][H_];   // 2 KB

    // stage qk[b] into LDS, coalesced float4
    {
        const float4* src = (const float4*)(qk + (size_t)b * H_ * E_);
        float4* dst = (float4*)qks;
        #pragma unroll
        for (int k = 0; k < 8; ++k) dst[t + k * 256] = src[t + k * 256];
    }
    __syncthreads();

    const float scale = 0.08838834764831845f;  // 1/sqrt(128)
    const float* keyb = key + ((size_t)b * N_ + (size_t)tile * TR_) * E_;
    const float4* qks4 = (const float4*)qks;
    const float qbv = qb[b * 8 + (c & 7)];     // lane c==h uses qb[b,h]

    // group g owns rows g*8..g*8+7, all in one pass
    float acc[H_][8];
    #pragma unroll
    for (int h = 0; h < H_; ++h)
        #pragma unroll
        for (int j = 0; j < 8; ++j) acc[h][j] = 0.f;

    const float4* kr[8];
    #pragma unroll
    for (int j = 0; j < 8; ++j)
        kr[j] = (const float4*)(keyb + (size_t)(g * 8 + j) * E_);

    #pragma unroll 2
    for (int i = 0; i < 8; ++i) {
        float4 kf[8];
        #pragma unroll
        for (int j = 0; j < 8; ++j) kf[j] = kr[j][i * 32 + c];
        #pragma unroll
        for (int h = 0; h < H_; ++h) {
            float4 qf = qks4[h * 256 + i * 32 + c];
            #pragma unroll
            for (int j = 0; j < 8; ++j) {
                acc[h][j] += qf.x * kf[j].x + qf.y * kf[j].y
                           + qf.z * kf[j].z + qf.w * kf[j].w;
            }
        }
    }
    // butterfly allreduce over the 32 lanes of this group (masks <32 never
    // cross the g boundary at lane bit 5)
    #pragma unroll
    for (int off = 16; off; off >>= 1) {
        #pragma unroll
        for (int h = 0; h < H_; ++h)
            #pragma unroll
            for (int j = 0; j < 8; ++j)
                acc[h][j] += __shfl_xor(acc[h][j], off);
    }
    // lanes c<8 store s for h=c (compile-time indices only, no scratch)
    float tsum = 0.f;
    #pragma unroll
    for (int h = 0; h < H_; ++h) {
        if (c == h) {
            #pragma unroll
            for (int j = 0; j < 8; ++j) {
                float s = (acc[h][j] + qbv) * scale;
                ssc[g * 8 + j][h] = s;
                tsum += s;
            }
        }
    }
    if (c < H_) atomicAdd(&ssum[b * 8 + c], tsum);
    __syncthreads();

    // phase 2: thread owns 4 e's; loop tile's 64 rows (L2/L3-hot re-read)
    {
        const int e0 = t * 4;
        float pacc[H_][4] = {};
        const float* kb = keyb + e0;
        #pragma unroll 4
        for (int n = 0; n < TR_; ++n) {
            float4 kv = *(const float4*)(kb + (size_t)n * E_);
            float4 s0 = *(const float4*)&ssc[n][0];
            float4 s1 = *(const float4*)&ssc[n][4];
            pacc[0][0] += s0.x * kv.x; pacc[0][1] += s0.x * kv.y;
            pacc[0][2] += s0.x * kv.z; pacc[0][3] += s0.x * kv.w;
            pacc[1][0] += s0.y * kv.x; pacc[1][1] += s0.y * kv.y;
            pacc[1][2] += s0.y * kv.z; pacc[1][3] += s0.y * kv.w;
            pacc[2][0] += s0.z * kv.x; pacc[2][1] += s0.z * kv.y;
            pacc[2][2] += s0.z * kv.z; pacc[2][3] += s0.z * kv.w;
            pacc[3][0] += s0.w * kv.x; pacc[3][1] += s0.w * kv.y;
            pacc[3][2] += s0.w * kv.z; pacc[3][3] += s0.w * kv.w;
            pacc[4][0] += s1.x * kv.x; pacc[4][1] += s1.x * kv.y;
            pacc[4][2] += s1.x * kv.z; pacc[4][3] += s1.x * kv.w;
            pacc[5][0] += s1.y * kv.x; pacc[5][1] += s1.y * kv.y;
            pacc[5][2] += s1.y * kv.z; pacc[5][3] += s1.y * kv.w;
            pacc[6][0] += s1.z * kv.x; pacc[6][1] += s1.z * kv.y;
            pacc[6][2] += s1.z * kv.z; pacc[6][3] += s1.z * kv.w;
            pacc[7][0] += s1.w * kv.x; pacc[7][1] += s1.w * kv.y;
            pacc[7][2] += s1.w * kv.z; pacc[7][3] += s1.w * kv.w;
        }
        #pragma unroll
        for (int h = 0; h < H_; ++h) {
            float* dst = PP + ((size_t)(b * H_) + h) * E_ + e0;
            atomicAdd(dst + 0, pacc[h][0]); atomicAdd(dst + 1, pacc[h][1]);
            atomicAdd(dst + 2, pacc[h][2]); atomicAdd(dst + 3, pacc[h][3]);
        }
    }
}

// ---------------------------------------------------------------------------
// K4: final. per (b,h), 256 threads.
//  attended_d = PP[b,h]·Wv_row(h*D+d) + ssum*bv_d
//  hv_m = relu(attended·Wb_m + bb_m)        (h constant over n → mask-pool = h)
//  alphac_d = sigmoid(sum_m hv_m*Wl2[d,m] + bl2_d)
//  v2a_d = P2[b]·Wv_row/cnt + bv_d          (softmax of uniform = mask/cnt)
//  out = f32(v1 * v2a * alphac)
// Wv dot layout: 16 lanes per d-row (lane reads 256B-contiguous float4 runs —
// the old one-thread-per-row layout had 64 lanes on 64 different 4KB-strided
// rows per instruction: fully uncoalesced).
// ---------------------------------------------------------------------------
__global__ __launch_bounds__(256) void k_final(
        const float* __restrict__ PP, const float* __restrict__ P2,
        const float* __restrict__ ssumg, const int* __restrict__ mask,
        const float* __restrict__ Wv, const float* __restrict__ bv,
        const float* __restrict__ Wb, const float* __restrict__ bb,
        const float* __restrict__ Wl2, const float* __restrict__ bl2,
        const float* __restrict__ value1, float* __restrict__ out)
{
    const int bh = blockIdx.x, b = bh >> 3, h = bh & 7;
    const int t = threadIdx.x;
    const int l = t & 63, w = t >> 6;       // 4 waves
    const int rg = l >> 4, cl = l & 15;     // 4 row-groups x 16 lanes

    __shared__ __align__(16) float pooled[E_];
    __shared__ __align__(16) float pool2[E_];
    __shared__ float attA_s[D_];
    __shared__ float attV_s[D_];
    __shared__ float att[D_];
    __shared__ float hv[MID_];
    __shared__ float red2[4];
    __shared__ float cnt_s;

    {
        const float4* pp = (const float4*)(PP + ((size_t)(b * H_) + h) * E_);
        const float4* p2 = (const float4*)(P2 + (size_t)b * E_);
        ((float4*)pooled)[t] = pp[t];
        ((float4*)pool2)[t]  = p2[t];

        int ci = 0;
        #pragma unroll
        for (int i = 0; i < 4; ++i) ci += mask[b * N_ + t + i * 256];
        float cf = (float)ci;
        #pragma unroll
        for (int off = 32; off; off >>= 1) cf += __shfl_down(cf, off);
        if (l == 0) red2[w] = cf;
    }
    __syncthreads();
    if (t == 0) cnt_s = red2[0] + red2[1] + red2[2] + red2[3];

    const float4* pooled4 = (const float4*)pooled;
    const float4* pool24  = (const float4*)pool2;
    #pragma unroll 2
    for (int pass = 0; pass < 8; ++pass) {
        const int d = pass * 16 + w * 4 + rg;     // each d in [0,128) exactly once
        const float4* wvr = (const float4*)(Wv + (size_t)(h * D_ + d) * E_);
        float pA = 0.f, pV = 0.f;
        #pragma unroll 4
        for (int i = 0; i < 16; ++i) {
            float4 wv4 = wvr[cl + i * 16];
            float4 pa = pooled4[cl + i * 16];
            float4 pb = pool24[cl + i * 16];
            pA += wv4.x * pa.x + wv4.y * pa.y + wv4.z * pa.z + wv4.w * pa.w;
            pV += wv4.x * pb.x + wv4.y * pb.y + wv4.z * pb.z + wv4.w * pb.w;
        }
        // reduce over the 16 lanes of this row-group (masks <16 stay in-group)
        #pragma unroll
        for (int off = 8; off; off >>= 1) {
            pA += __shfl_xor(pA, off);
            pV += __shfl_xor(pV, off);
        }
        if (cl == 0) { attA_s[d] = pA; attV_s[d] = pV; }
    }
    __syncthreads();
    const float cnt = cnt_s;
    const float ss = ssumg[bh];
    if (t < D_) att[t] = attA_s[t] + ss * bv[h * D_ + t];
    __syncthreads();
    if (t < MID_) {
        float a = bb[t];
        #pragma unroll 4
        for (int d2 = 0; d2 < D_; ++d2) a += att[d2] * Wb[t * D_ + d2];
        hv[t] = fmaxf(a, 0.f);
    }
    __syncthreads();
    if (t < D_) {
        float z = bl2[t];
        #pragma unroll
        for (int m = 0; m < MID_; ++m) z += hv[m] * Wl2[t * MID_ + m];
        float alphac = 1.f / (1.f + expf(-z));
        const float bvd = bv[h * D_ + t];
        float v2a = attV_s[t] / cnt + bvd;
        out[(size_t)b * E_ + h * D_ + t] =
            value1[(size_t)b * E_ + h * D_ + t] * v2a * alphac;
    }
}

// ---------------------------------------------------------------------------
extern "C" void kernel_launch(void* const* d_in, const int* in_sizes, int n_in,
                              void* d_out, int out_size, void* d_ws, size_t ws_size,
                              hipStream_t stream)
{
    const float* query  = (const float*)d_in[0];
    const float* key    = (const float*)d_in[1];
    const int*   mask   = (const int*)d_in[2];
    const float* value1 = (const float*)d_in[3];
    const float* value2 = (const float*)d_in[4];
    const float* Wq  = (const float*)d_in[5];
    const float* bq  = (const float*)d_in[6];
    const float* Wk  = (const float*)d_in[7];
    const float* bk  = (const float*)d_in[8];
    const float* Wv  = (const float*)d_in[9];
    const float* bv  = (const float*)d_in[10];
    const float* Wb  = (const float*)d_in[11];
    const float* bb  = (const float*)d_in[12];
    // d_in[13] = Wl, d_in[14] = bl: eliminated (softmax over identical values = mask/cnt)
    const float* Wl2 = (const float*)d_in[15];
    const float* bl2 = (const float*)d_in[16];
    float* out = (float*)d_out;

    // workspace layout (bytes), total ~2.13 MB
    char* ws = (char*)d_ws;
    const size_t OFF_P2 = (size_t)B_ * H_ * E_ * 4;     // PP: 1 MB
    const size_t OFF_SS = OFF_P2 + (size_t)B_ * E_ * 4; // P2: 128 KB
    const size_t OFF_QB = OFF_SS + 1024;                // ssum: 1 KB
    const size_t OFF_QK = OFF_QB + 1024;                // qb: 1 KB
    float* PP   = (float*)(ws);
    float* P2   = (float*)(ws + OFF_P2);
    float* ssum = (float*)(ws + OFF_SS);
    float* qb   = (float*)(ws + OFF_QB);
    float* qk   = (float*)(ws + OFF_QK);                // 1 MB

    // zero the atomic-accumulated region (PP, P2, ssum); stream-ordered, capture-safe
    hipMemsetAsync(d_ws, 0, OFF_QB, stream);

    hipLaunchKernelGGL(k_pre, dim3(256 + NS2_ * B_), dim3(256), 0, stream,
                       query, Wq, bq, Wk, bk, qk, qb, value2, mask, P2);
    hipLaunchKernelGGL(k_scorepool, dim3(NT_, B_), dim3(256), 0, stream,
                       key, qk, qb, PP, ssum);
    hipLaunchKernelGGL(k_final, dim3(B_ * H_), dim3(256), 0, stream,
                       PP, P2, ssum, mask, Wv, bv, Wb, bb, Wl2, bl2, value1, out);
}